// Round 8
// baseline (129.317 us; speedup 1.0000x reference)
//
#include <hip/hip_runtime.h>
#include <hip/hip_bf16.h>
#include <math.h>

#define Bn 8
#define Tn 2048
#define Cn 1024
#define Hn 64

typedef __attribute__((ext_vector_type(8))) short short8;
typedef __attribute__((ext_vector_type(4))) float floatx4;
typedef __attribute__((ext_vector_type(4))) _Float16 half4;

#define ATTN_SCALE 0.18033688011112042f   // log2(e) / sqrt(64)

__device__ inline unsigned short f2bf(float f) {
    union { float f; unsigned int u; } x; x.f = f;
    unsigned int r = x.u + 0x7fffu + ((x.u >> 16) & 1u);
    return (unsigned short)(r >> 16);
}

__device__ inline uint2 pack4bf(float4 v) {
    __hip_bfloat162 lo = __float22bfloat162_rn(make_float2(v.x, v.y));
    __hip_bfloat162 hi = __float22bfloat162_rn(make_float2(v.z, v.w));
    uint2 r;
    r.x = *reinterpret_cast<unsigned int*>(&lo);
    r.y = *reinterpret_cast<unsigned int*>(&hi);
    return r;
}

// ---------------------------------------------------------------------------
// Kernel 0: W -> bf16 in MFMA B-FRAGMENT ORDER.  (unchanged)
// ---------------------------------------------------------------------------
__global__ __launch_bounds__(256) void prep_w(
    const float* __restrict__ Wq, const float* __restrict__ Wk,
    const float* __restrict__ Wv, unsigned short* __restrict__ Wfrag)
{
    const int gid = blockIdx.x * 256 + threadIdx.x;   // 0..24575
    const int c    = gid >> 11;
    const int rem  = gid & 2047;
    const int ks   = rem >> 6;
    const int lane = rem & 63;
    const int ln = lane & 15, qd = lane >> 4;
    const int mat = c >> 2, nc = c & 3;
    const float* W = (mat == 0) ? Wq : (mat == 1) ? Wk : Wv;
    const float sc = (mat == 0) ? ATTN_SCALE : 1.0f;
    const int col = nc * 16 + ln;
    unsigned short o[8];
    #pragma unroll
    for (int j = 0; j < 8; ++j)
        o[j] = f2bf(W[(size_t)(ks * 32 + qd * 8 + j) * Hn + col] * sc);
    *reinterpret_cast<short8*>(Wfrag + (size_t)gid * 8) = *reinterpret_cast<short8*>(o);
}

// ---------------------------------------------------------------------------
// Kernel 1: fused QKV projection.  (round-7 structure, frozen except the V
// branch of the epilogue, which now emits FP16 in K=16 B-fragment order:
//   vfrag16[((b*128 + t16)*4 + c)*64 + (ln + 16*qd)][j] = V[t16*16+qd*4+j][c*16+ln]
// so attention's PV MFMA (16x16x16 f16) can load it as contiguous ushort4.)
// ---------------------------------------------------------------------------
__global__ __launch_bounds__(256, 4) void proj_mfma(
    const float* __restrict__ x, const unsigned short* __restrict__ Wfrag,
    unsigned short* __restrict__ qbf, unsigned short* __restrict__ kfrag,
    unsigned short* __restrict__ vfrag)
{
    __shared__ unsigned short xs[32 * 512];     // 32 KB

    const int ln   = threadIdx.x & 15;
    const int quad = (threadIdx.x >> 4) & 3;
    const int w    = threadIdx.x >> 6;
    const int lane = threadIdx.x & 63;
    const int row0 = blockIdx.x * 16;

    // ---- phase 1: stage x tile (A-fragment order, coalesced) ----
    const int srow = threadIdx.x >> 4;
    const int sf   = threadIdx.x & 15;
    const float4* xrow4 = reinterpret_cast<const float4*>(x + (size_t)(row0 + srow) * Cn);

    float4 ld[16];
    #pragma unroll
    for (int it = 0; it < 16; ++it)
        ld[it] = xrow4[sf + 16 * it];
    #pragma unroll
    for (int it = 0; it < 16; ++it) {
        const int f4g = sf + 16 * it;
        const int s = f4g >> 3;
        const int q = (f4g >> 1) & 3;
        const int j = (f4g & 1) * 4;
        *reinterpret_cast<uint2*>(&xs[s * 512 + (q * 16 + srow) * 8 + j]) = pack4bf(ld[it]);
    }
    __syncthreads();

    // ---- phase 2: barrier-free MFMA stream ----
    floatx4 acc[3];
    #pragma unroll
    for (int i = 0; i < 3; ++i) acc[i] = (floatx4){0.f, 0.f, 0.f, 0.f};

    #pragma unroll 4
    for (int s = 0; s < 32; ++s) {
        const short8 a = *reinterpret_cast<const short8*>(&xs[s * 512 + lane * 8]);
        #pragma unroll
        for (int i = 0; i < 3; ++i) {
            const int cc = w * 3 + i;
            const short8 b = *reinterpret_cast<const short8*>(
                Wfrag + ((size_t)(cc * 32 + s) * 64 + lane) * 8);
            acc[i] = __builtin_amdgcn_mfma_f32_16x16x32_bf16(a, b, acc[i], 0, 0, 0);
        }
    }

    // epilogue: C layout col = ln, row = quad*4 + r
    const int t0   = row0 + quad * 4;
    const int b    = t0 >> 11;
    const int tloc = t0 & 2047;
    #pragma unroll
    for (int i = 0; i < 3; ++i) {
        const int idx = w * 3 + i;
        const int mat = idx >> 2, ch = idx & 3;
        if (mat == 0) {
            #pragma unroll
            for (int r = 0; r < 4; ++r)
                qbf[(size_t)(t0 + r) * Hn + ch * 16 + ln] = f2bf(acc[i][r]);
        } else if (mat == 1) {
            const int kc = tloc >> 4;
            const int ks = ch >> 1;
            const int lq = (ch & 1) * 2 + (ln >> 3);
            #pragma unroll
            for (int r = 0; r < 4; ++r) {
                const int lanep = (quad * 4 + r) + 16 * lq;
                kfrag[(((size_t)(b * 128 + kc) * 2 + ks) * 64 + lanep) * 8 + (ln & 7)]
                    = f2bf(acc[i][r]);
            }
        } else {
            // V -> fp16, K=16 B-frag order: tile t16 = tloc>>4, qd'=quad, j=r
            const int t16 = tloc >> 4;
            union { _Float16 h[4]; ushort4 u; } cv;
            cv.h[0] = (_Float16)acc[i][0]; cv.h[1] = (_Float16)acc[i][1];
            cv.h[2] = (_Float16)acc[i][2]; cv.h[3] = (_Float16)acc[i][3];
            *reinterpret_cast<ushort4*>(
                vfrag + (((size_t)(b * 128 + t16) * 4 + ch) * 64 + ln + 16 * quad) * 4) = cv.u;
        }
    }
}

// ---------------------------------------------------------------------------
// Kernel 2: causal flash attention — S-TRANSPOSE, ZERO-SHUFFLE P->PV.
// Per 16-key tile:  S^T = K Q^T via 2x mfma_16x16x32_bf16 (A = kfrag as-is,
// B = q as-is).  C-layout of S^T: lane(ln,qd) reg r = P[q=ln][key=qd*4+r],
// which IS the A-frag layout of mfma_f32_16x16x16_f16 (A[m=ln][k=qd*4+j]).
// So: exp2 -> cvt f16 -> PV MFMA directly; no LDS round-trip, no waitcnt.
// V read in matching K=16 B-frag order (fp16, contiguous ushort4/lane).
// l: per-lane partial, one cross-quad shfl reduce at end.
// 4 waves split the key range; merge through LDS (unchanged).
// ---------------------------------------------------------------------------
__global__ __launch_bounds__(256, 4) void attn_mfma(
    const unsigned short* __restrict__ qbf, const unsigned short* __restrict__ kfrag,
    const unsigned short* __restrict__ vfrag, float* __restrict__ out)
{
    __shared__ float o_lds[4][16][68];               // 17.4 KB
    __shared__ float l_lds[4][16];

    const int j  = blockIdx.x;
    const int b  = j & 7;
    const int ti = 127 - (j >> 3);                   // heavy tiles first
    const int q0 = ti * 16;

    const int ln   = threadIdx.x & 15;
    const int quad = (threadIdx.x >> 4) & 3;
    const int w    = threadIdx.x >> 6;
    const int lane = threadIdx.x & 63;

    const unsigned short* qb = qbf + (size_t)b * Tn * Hn;
    const unsigned short* Kb = kfrag + (size_t)b * 131072;
    const unsigned short* Vb = vfrag + (size_t)b * 131072;

    // Q as B-frag: lane(ln,qd) = Q[q=ln][d = h*32 + qd*8 + j]
    const short8 aq0 = *reinterpret_cast<const short8*>(qb + (size_t)(q0 + ln) * Hn + quad * 8);
    const short8 aq1 = *reinterpret_cast<const short8*>(qb + (size_t)(q0 + ln) * Hn + 32 + quad * 8);

    floatx4 O[4];
    #pragma unroll
    for (int c = 0; c < 4; ++c) O[c] = (floatx4){0.f, 0.f, 0.f, 0.f};
    float lp = 0.f;

    const int ntiles = ti + 1;                       // 16-key tiles
    const int per    = (ntiles + 3) >> 2;
    const int beg    = w * per;
    const int end    = min(beg + per, ntiles);

    union U4 { ushort4 u; half4 h; };
    short8 kf0, kf1; U4 vf[4];
    if (beg < end) {
        kf0 = *reinterpret_cast<const short8*>(Kb + (size_t)(beg * 2) * 512 + lane * 8);
        kf1 = *reinterpret_cast<const short8*>(Kb + (size_t)(beg * 2 + 1) * 512 + lane * 8);
        #pragma unroll
        for (int c = 0; c < 4; ++c)
            vf[c].u = *reinterpret_cast<const ushort4*>(Vb + (size_t)(beg * 4 + c) * 256 + lane * 4);
    }

    for (int t = beg; t < end; ++t) {
        const int tn = (t + 1 < end) ? (t + 1) : t;
        short8 kn0, kn1; U4 vn[4];
        kn0 = *reinterpret_cast<const short8*>(Kb + (size_t)(tn * 2) * 512 + lane * 8);
        kn1 = *reinterpret_cast<const short8*>(Kb + (size_t)(tn * 2 + 1) * 512 + lane * 8);
        #pragma unroll
        for (int c = 0; c < 4; ++c)
            vn[c].u = *reinterpret_cast<const ushort4*>(Vb + (size_t)(tn * 4 + c) * 256 + lane * 4);

        // S^T = K Q^T : D[m=key=quad*4+r][n=q=ln]
        const floatx4 z = (floatx4){0.f, 0.f, 0.f, 0.f};
        floatx4 St = __builtin_amdgcn_mfma_f32_16x16x32_bf16(kf0, aq0, z, 0, 0, 0);
        St = __builtin_amdgcn_mfma_f32_16x16x32_bf16(kf1, aq1, St, 0, 0, 0);

        const bool diag = (t == ntiles - 1);
        half4 pa;
        #pragma unroll
        for (int r = 0; r < 4; ++r) {
            float sv = St[r];
            if (diag && (quad * 4 + r > ln)) sv = -1e30f;   // key offset > query offset
            const float p = exp2f(sv);
            lp += p;
            pa[r] = (_Float16)p;
        }
        #pragma unroll
        for (int c = 0; c < 4; ++c)
            O[c] = __builtin_amdgcn_mfma_f32_16x16x16f16(pa, vf[c].h, O[c], 0, 0, 0);

        kf0 = kn0; kf1 = kn1;
        #pragma unroll
        for (int c = 0; c < 4; ++c) vf[c] = vn[c];
    }

    // stash per-wave partials (empty strips contribute zeros)
    #pragma unroll
    for (int c = 0; c < 4; ++c)
        #pragma unroll
        for (int r = 0; r < 4; ++r)
            o_lds[w][quad * 4 + r][c * 16 + ln] = O[c][r];
    // l[q=ln] = sum over this wave's keys: reduce the 4 quads
    {
        float lt = lp;
        lt += __shfl_xor(lt, 16);
        lt += __shfl_xor(lt, 32);
        if (quad == 0) l_lds[w][ln] = lt;
    }
    __syncthreads();

    // merge: thread -> (row qq of 16, dim-quad dg of 16)
    const int qq = threadIdx.x >> 4;
    const int dg = threadIdx.x & 15;
    const float ltot = l_lds[0][qq] + l_lds[1][qq] + l_lds[2][qq] + l_lds[3][qq];
    const float inv = 1.0f / ltot;
    const float4 a0 = *reinterpret_cast<float4*>(&o_lds[0][qq][dg * 4]);
    const float4 a1 = *reinterpret_cast<float4*>(&o_lds[1][qq][dg * 4]);
    const float4 a2 = *reinterpret_cast<float4*>(&o_lds[2][qq][dg * 4]);
    const float4 a3 = *reinterpret_cast<float4*>(&o_lds[3][qq][dg * 4]);
    float4 r;
    r.x = (a0.x + a1.x + a2.x + a3.x) * inv;
    r.y = (a0.y + a1.y + a2.y + a3.y) * inv;
    r.z = (a0.z + a1.z + a2.z + a3.z) * inv;
    r.w = (a0.w + a1.w + a2.w + a3.w) * inv;
    *reinterpret_cast<float4*>(out + ((size_t)b * Tn + q0 + qq) * Hn + dg * 4) = r;
}

// ---------------------------------------------------------------------------
extern "C" void kernel_launch(void* const* d_in, const int* in_sizes, int n_in,
                              void* d_out, int out_size, void* d_ws, size_t ws_size,
                              hipStream_t stream) {
    (void)in_sizes; (void)n_in; (void)out_size; (void)ws_size;
    const float* x  = (const float*)d_in[0];
    const float* Wq = (const float*)d_in[1];
    const float* Wk = (const float*)d_in[2];
    const float* Wv = (const float*)d_in[3];
    float* out = (float*)d_out;

    unsigned short* Wfrag = (unsigned short*)d_ws;            // 196608
    unsigned short* qbf   = Wfrag + (size_t)196608;           // 1048576
    unsigned short* kfr   = qbf + (size_t)Bn * Tn * Hn;       // 1048576
    unsigned short* vfr   = kfr + (size_t)Bn * 131072;        // 1048576 (fp16)

    prep_w<<<96, 256, 0, stream>>>(Wq, Wk, Wv, Wfrag);
    proj_mfma<<<(Bn * Tn) / 16, 256, 0, stream>>>(x, Wfrag, qbf, kfr, vfr);
    attn_mfma<<<Bn * (Tn / 16), 256, 0, stream>>>(qbf, kfr, vfr, out);
}

// Round 9
// 125.642 us; speedup vs baseline: 1.0293x; 1.0293x over previous
//
#include <hip/hip_runtime.h>
#include <hip/hip_bf16.h>
#include <math.h>

#define Bn 8
#define Tn 2048
#define Cn 1024
#define Hn 64

typedef __attribute__((ext_vector_type(8))) short short8;
typedef __attribute__((ext_vector_type(4))) float floatx4;
typedef __attribute__((ext_vector_type(8))) _Float16 half8;

#define ATTN_SCALE 0.18033688011112042f   // log2(e) / sqrt(64)

__device__ inline unsigned short f2bf(float f) {
    union { float f; unsigned int u; } x; x.f = f;
    unsigned int r = x.u + 0x7fffu + ((x.u >> 16) & 1u);
    return (unsigned short)(r >> 16);
}

__device__ inline uint2 pack4bf(float4 v) {
    __hip_bfloat162 lo = __float22bfloat162_rn(make_float2(v.x, v.y));
    __hip_bfloat162 hi = __float22bfloat162_rn(make_float2(v.z, v.w));
    uint2 r;
    r.x = *reinterpret_cast<unsigned int*>(&lo);
    r.y = *reinterpret_cast<unsigned int*>(&hi);
    return r;
}

// ---------------------------------------------------------------------------
// Kernel 0: W -> bf16 in MFMA B-FRAGMENT ORDER.  (unchanged)
// ---------------------------------------------------------------------------
__global__ __launch_bounds__(256) void prep_w(
    const float* __restrict__ Wq, const float* __restrict__ Wk,
    const float* __restrict__ Wv, unsigned short* __restrict__ Wfrag)
{
    const int gid = blockIdx.x * 256 + threadIdx.x;   // 0..24575
    const int c    = gid >> 11;
    const int rem  = gid & 2047;
    const int ks   = rem >> 6;
    const int lane = rem & 63;
    const int ln = lane & 15, qd = lane >> 4;
    const int mat = c >> 2, nc = c & 3;
    const float* W = (mat == 0) ? Wq : (mat == 1) ? Wk : Wv;
    const float sc = (mat == 0) ? ATTN_SCALE : 1.0f;
    const int col = nc * 16 + ln;
    unsigned short o[8];
    #pragma unroll
    for (int j = 0; j < 8; ++j)
        o[j] = f2bf(W[(size_t)(ks * 32 + qd * 8 + j) * Hn + col] * sc);
    *reinterpret_cast<short8*>(Wfrag + (size_t)gid * 8) = *reinterpret_cast<short8*>(o);
}

// ---------------------------------------------------------------------------
// Kernel 1: fused QKV projection.  (round-7 structure; only the V epilogue
// branch differs: fp16, K=32 PERMUTED B-frag order.  For 32-key tile t32,
// key-in-tile = h*16 + quad*4 + r maps to frag element j = h*4 + r:
//   vfrag[(((b*64+t32)*4+ch)*64 + ln+16*quad)*8 + h*4 + r]
//     = (fp16) V[t32*32 + h*16 + quad*4 + r][ch*16+ln]
// matching attn's pa[j] assembly from the two S^T halves.)
// ---------------------------------------------------------------------------
__global__ __launch_bounds__(256, 4) void proj_mfma(
    const float* __restrict__ x, const unsigned short* __restrict__ Wfrag,
    unsigned short* __restrict__ qbf, unsigned short* __restrict__ kfrag,
    unsigned short* __restrict__ vfrag)
{
    __shared__ unsigned short xs[32 * 512];     // 32 KB

    const int ln   = threadIdx.x & 15;
    const int quad = (threadIdx.x >> 4) & 3;
    const int w    = threadIdx.x >> 6;
    const int lane = threadIdx.x & 63;
    const int row0 = blockIdx.x * 16;

    // ---- phase 1: stage x tile (A-fragment order, coalesced) ----
    const int srow = threadIdx.x >> 4;
    const int sf   = threadIdx.x & 15;
    const float4* xrow4 = reinterpret_cast<const float4*>(x + (size_t)(row0 + srow) * Cn);

    float4 ld[16];
    #pragma unroll
    for (int it = 0; it < 16; ++it)
        ld[it] = xrow4[sf + 16 * it];
    #pragma unroll
    for (int it = 0; it < 16; ++it) {
        const int f4g = sf + 16 * it;
        const int s = f4g >> 3;
        const int q = (f4g >> 1) & 3;
        const int j = (f4g & 1) * 4;
        *reinterpret_cast<uint2*>(&xs[s * 512 + (q * 16 + srow) * 8 + j]) = pack4bf(ld[it]);
    }
    __syncthreads();

    // ---- phase 2: barrier-free MFMA stream ----
    floatx4 acc[3];
    #pragma unroll
    for (int i = 0; i < 3; ++i) acc[i] = (floatx4){0.f, 0.f, 0.f, 0.f};

    #pragma unroll 4
    for (int s = 0; s < 32; ++s) {
        const short8 a = *reinterpret_cast<const short8*>(&xs[s * 512 + lane * 8]);
        #pragma unroll
        for (int i = 0; i < 3; ++i) {
            const int cc = w * 3 + i;
            const short8 b = *reinterpret_cast<const short8*>(
                Wfrag + ((size_t)(cc * 32 + s) * 64 + lane) * 8);
            acc[i] = __builtin_amdgcn_mfma_f32_16x16x32_bf16(a, b, acc[i], 0, 0, 0);
        }
    }

    // epilogue: C layout col = ln, row = quad*4 + r
    const int t0   = row0 + quad * 4;
    const int b    = t0 >> 11;
    const int tloc = t0 & 2047;
    #pragma unroll
    for (int i = 0; i < 3; ++i) {
        const int idx = w * 3 + i;
        const int mat = idx >> 2, ch = idx & 3;
        if (mat == 0) {
            #pragma unroll
            for (int r = 0; r < 4; ++r)
                qbf[(size_t)(t0 + r) * Hn + ch * 16 + ln] = f2bf(acc[i][r]);
        } else if (mat == 1) {
            const int kc = tloc >> 4;
            const int ks = ch >> 1;
            const int lq = (ch & 1) * 2 + (ln >> 3);
            #pragma unroll
            for (int r = 0; r < 4; ++r) {
                const int lanep = (quad * 4 + r) + 16 * lq;
                kfrag[(((size_t)(b * 128 + kc) * 2 + ks) * 64 + lanep) * 8 + (ln & 7)]
                    = f2bf(acc[i][r]);
            }
        } else {
            // V -> fp16, K=32 permuted B-frag order
            const int t32 = tloc >> 5;
            const int h16 = (tloc >> 4) & 1;
            union { _Float16 h[4]; ushort4 u; } cv;
            cv.h[0] = (_Float16)acc[i][0]; cv.h[1] = (_Float16)acc[i][1];
            cv.h[2] = (_Float16)acc[i][2]; cv.h[3] = (_Float16)acc[i][3];
            *reinterpret_cast<ushort4*>(
                vfrag + (((size_t)(b * 64 + t32) * 4 + ch) * 64 + ln + 16 * quad) * 8
                      + h16 * 4) = cv.u;
        }
    }
}

// ---------------------------------------------------------------------------
// Kernel 2: causal flash attention — S-TRANSPOSE, 32-KEY TILES, ZERO LDS
// on the P path.  Per 32-key tile:
//   St0/St1 = K Q^T for the two 16-key halves (2x mfma 16x16x32 bf16 each
//   half... 2 MFMAs per half over the 64 dims -> 4 S-MFMAs total).
//   Lane (ln,qd) reg r: St_h[r] = S[key = t*32 + h*16 + qd*4 + r][q = ln].
//   pa[j] = exp2: j<4 -> St0[j], j>=4 -> St1[j-4]  == A-frag of K=32 f16
//   MFMA under the permuted key enumeration baked into vfrag.
//   4 PV MFMAs (c-chunks), K=32 f16.  No LDS round-trip, no waitcnt.
// 4 waves split the key range; merge through LDS (unchanged).
// ---------------------------------------------------------------------------
__global__ __launch_bounds__(256, 4) void attn_mfma(
    const unsigned short* __restrict__ qbf, const unsigned short* __restrict__ kfrag,
    const unsigned short* __restrict__ vfrag, float* __restrict__ out)
{
    __shared__ float o_lds[4][16][68];               // 17.4 KB
    __shared__ float l_lds[4][16];

    const int j  = blockIdx.x;
    const int b  = j & 7;
    const int ti = 127 - (j >> 3);                   // heavy tiles first
    const int q0 = ti * 16;

    const int ln   = threadIdx.x & 15;
    const int quad = (threadIdx.x >> 4) & 3;
    const int w    = threadIdx.x >> 6;
    const int lane = threadIdx.x & 63;

    const unsigned short* qb = qbf + (size_t)b * Tn * Hn;
    const unsigned short* Kb = kfrag + (size_t)b * 131072;
    const unsigned short* Vb = vfrag + (size_t)b * 131072;

    // Q as B-frag: lane(ln,qd) = Q[q=ln][d = h*32 + qd*8 + j]
    const short8 aq0 = *reinterpret_cast<const short8*>(qb + (size_t)(q0 + ln) * Hn + quad * 8);
    const short8 aq1 = *reinterpret_cast<const short8*>(qb + (size_t)(q0 + ln) * Hn + 32 + quad * 8);

    floatx4 O[4];
    #pragma unroll
    for (int c = 0; c < 4; ++c) O[c] = (floatx4){0.f, 0.f, 0.f, 0.f};
    float lp = 0.f;

    const int ntiles = (q0 + 47) >> 5;               // 32-key tiles
    const int per    = (ntiles + 3) >> 2;
    const int beg    = w * per;
    const int end    = min(beg + per, ntiles);

    short8 kf[4]; half8 vf[4];
    if (beg < end) {
        #pragma unroll
        for (int u = 0; u < 4; ++u) {
            kf[u] = *reinterpret_cast<const short8*>(Kb + (size_t)(beg * 4 + u) * 512 + lane * 8);
            vf[u] = *reinterpret_cast<const half8*>(Vb + (size_t)(beg * 4 + u) * 512 + lane * 8);
        }
    }

    for (int t = beg; t < end; ++t) {
        const int tn = (t + 1 < end) ? (t + 1) : t;
        short8 kn[4]; half8 vn[4];
        #pragma unroll
        for (int u = 0; u < 4; ++u) {
            kn[u] = *reinterpret_cast<const short8*>(Kb + (size_t)(tn * 4 + u) * 512 + lane * 8);
            vn[u] = *reinterpret_cast<const half8*>(Vb + (size_t)(tn * 4 + u) * 512 + lane * 8);
        }

        // S^T halves: kf[2s+h] = K[key half s][dim half h]
        const floatx4 z = (floatx4){0.f, 0.f, 0.f, 0.f};
        floatx4 St0 = __builtin_amdgcn_mfma_f32_16x16x32_bf16(kf[0], aq0, z, 0, 0, 0);
        St0 = __builtin_amdgcn_mfma_f32_16x16x32_bf16(kf[1], aq1, St0, 0, 0, 0);
        floatx4 St1 = __builtin_amdgcn_mfma_f32_16x16x32_bf16(kf[2], aq0, z, 0, 0, 0);
        St1 = __builtin_amdgcn_mfma_f32_16x16x32_bf16(kf[3], aq1, St1, 0, 0, 0);

        const bool diag = (t == ntiles - 1);
        const int koff = t * 32 - q0;                // only used when diag
        half8 pa;
        #pragma unroll
        for (int r = 0; r < 4; ++r) {
            float s0 = St0[r], s1 = St1[r];
            if (diag) {
                if (koff + quad * 4 + r > ln)      s0 = -1e30f;
                if (koff + 16 + quad * 4 + r > ln) s1 = -1e30f;
            }
            const float p0 = exp2f(s0);
            const float p1 = exp2f(s1);
            lp += p0 + p1;
            pa[r]     = (_Float16)p0;
            pa[r + 4] = (_Float16)p1;
        }
        #pragma unroll
        for (int c = 0; c < 4; ++c)
            O[c] = __builtin_amdgcn_mfma_f32_16x16x32_f16(pa, vf[c], O[c], 0, 0, 0);

        #pragma unroll
        for (int u = 0; u < 4; ++u) { kf[u] = kn[u]; vf[u] = vn[u]; }
    }

    // stash per-wave partials (empty strips contribute zeros)
    #pragma unroll
    for (int c = 0; c < 4; ++c)
        #pragma unroll
        for (int r = 0; r < 4; ++r)
            o_lds[w][quad * 4 + r][c * 16 + ln] = O[c][r];
    // l[q=ln]: reduce the 4 quads
    {
        float lt = lp;
        lt += __shfl_xor(lt, 16);
        lt += __shfl_xor(lt, 32);
        if (quad == 0) l_lds[w][ln] = lt;
    }
    __syncthreads();

    // merge: thread -> (row qq of 16, dim-quad dg of 16)
    const int qq = threadIdx.x >> 4;
    const int dg = threadIdx.x & 15;
    const float ltot = l_lds[0][qq] + l_lds[1][qq] + l_lds[2][qq] + l_lds[3][qq];
    const float inv = 1.0f / ltot;
    const float4 a0 = *reinterpret_cast<float4*>(&o_lds[0][qq][dg * 4]);
    const float4 a1 = *reinterpret_cast<float4*>(&o_lds[1][qq][dg * 4]);
    const float4 a2 = *reinterpret_cast<float4*>(&o_lds[2][qq][dg * 4]);
    const float4 a3 = *reinterpret_cast<float4*>(&o_lds[3][qq][dg * 4]);
    float4 r;
    r.x = (a0.x + a1.x + a2.x + a3.x) * inv;
    r.y = (a0.y + a1.y + a2.y + a3.y) * inv;
    r.z = (a0.z + a1.z + a2.z + a3.z) * inv;
    r.w = (a0.w + a1.w + a2.w + a3.w) * inv;
    *reinterpret_cast<float4*>(out + ((size_t)b * Tn + q0 + qq) * Hn + dg * 4) = r;
}

// ---------------------------------------------------------------------------
extern "C" void kernel_launch(void* const* d_in, const int* in_sizes, int n_in,
                              void* d_out, int out_size, void* d_ws, size_t ws_size,
                              hipStream_t stream) {
    (void)in_sizes; (void)n_in; (void)out_size; (void)ws_size;
    const float* x  = (const float*)d_in[0];
    const float* Wq = (const float*)d_in[1];
    const float* Wk = (const float*)d_in[2];
    const float* Wv = (const float*)d_in[3];
    float* out = (float*)d_out;

    unsigned short* Wfrag = (unsigned short*)d_ws;            // 196608
    unsigned short* qbf   = Wfrag + (size_t)196608;           // 1048576
    unsigned short* kfr   = qbf + (size_t)Bn * Tn * Hn;       // 1048576
    unsigned short* vfr   = kfr + (size_t)Bn * 131072;        // 1048576 (fp16)

    prep_w<<<96, 256, 0, stream>>>(Wq, Wk, Wv, Wfrag);
    proj_mfma<<<(Bn * Tn) / 16, 256, 0, stream>>>(x, Wfrag, qbf, kfr, vfr);
    attn_mfma<<<Bn * (Tn / 16), 256, 0, stream>>>(qbf, kfr, vfr, out);
}